// Round 7
// baseline (173.612 us; speedup 1.0000x reference)
//
#include <hip/hip_runtime.h>
#include <hip/hip_bf16.h>

#define B_   16
#define N_   1024
#define INF_ 256
#define NH_  4
#define HD_  256
#define L2E  1.4426950408889634f

typedef __attribute__((ext_vector_type(8))) short short8;
typedef __attribute__((ext_vector_type(4))) float f32x4;

__device__ __forceinline__ float bf2f(unsigned short u) {
    union { unsigned int i; float f; } v; v.i = ((unsigned int)u) << 16; return v.f;
}
__device__ __forceinline__ unsigned short f2bf(float f) {
    union { float f; unsigned int i; } v; v.f = f;
    unsigned int x = v.i;
    return (unsigned short)((x + 0x7fffu + ((x >> 16) & 1u)) >> 16);
}

// ---------------------------------------------------------------------------
// Kernel P: W (256x256 fp32) -> wswz bf16 in MFMA B-frag order. grid=32.
// slot = (kstep*16 + ntile)*64 + lane; elem q: k=kstep*32+(lane>>4)*8+q,
// n = ntile*16 + (lane&15).
// ---------------------------------------------------------------------------
__global__ __launch_bounds__(256) void k_prepw(const float* __restrict__ W,
                                               unsigned short* __restrict__ wswz)
{
    int slot = blockIdx.x * 256 + threadIdx.x;
    int kstep = slot >> 10;
    int nt    = (slot >> 6) & 15;
    int lane  = slot & 63;
    int k0 = kstep * 32 + (lane >> 4) * 8;
    int n  = nt * 16 + (lane & 15);
    ushort4 o0, o1;
    o0.x = f2bf(W[(k0 + 0) * HD_ + n]);
    o0.y = f2bf(W[(k0 + 1) * HD_ + n]);
    o0.z = f2bf(W[(k0 + 2) * HD_ + n]);
    o0.w = f2bf(W[(k0 + 3) * HD_ + n]);
    o1.x = f2bf(W[(k0 + 4) * HD_ + n]);
    o1.y = f2bf(W[(k0 + 5) * HD_ + n]);
    o1.z = f2bf(W[(k0 + 6) * HD_ + n]);
    o1.w = f2bf(W[(k0 + 7) * HD_ + n]);
    *(ushort4*)&wswz[(long)slot * 8]     = o0;
    *(ushort4*)&wswz[(long)slot * 8 + 4] = o1;
}

// ---------------------------------------------------------------------------
// Kernel A: h = x @ W via MFMA, W-frags from L2 in-loop (round-4/6 form).
// Block = 256 thr = 4 waves (one head each), 16 rows. grid = 1024.
// Emits hswz (B-frag order bf16) + scores pre-scaled by log2(e).
// ---------------------------------------------------------------------------
__global__ __launch_bounds__(256) void k_gemm_h(
    const float* __restrict__ x, const float* __restrict__ a,
    const unsigned short* __restrict__ wswz,
    unsigned short* __restrict__ hswz,
    float* __restrict__ ssrc, float* __restrict__ sdst)
{
    __shared__ unsigned short xls[16][264];
    int t = threadIdx.x;
    int blk = blockIdx.x;
    int row0 = blk * 16;
    int b  = blk >> 6;
    int n0 = row0 & 1023;

    {
        int sr = t >> 4, sc = (t & 15) * 16;
        const float* xp = x + (long)(row0 + sr) * INF_ + sc;
        float4 v0 = ((const float4*)xp)[0];
        float4 v1 = ((const float4*)xp)[1];
        float4 v2 = ((const float4*)xp)[2];
        float4 v3 = ((const float4*)xp)[3];
        ushort4 u0 = {f2bf(v0.x), f2bf(v0.y), f2bf(v0.z), f2bf(v0.w)};
        ushort4 u1 = {f2bf(v1.x), f2bf(v1.y), f2bf(v1.z), f2bf(v1.w)};
        ushort4 u2 = {f2bf(v2.x), f2bf(v2.y), f2bf(v2.z), f2bf(v2.w)};
        ushort4 u3 = {f2bf(v3.x), f2bf(v3.y), f2bf(v3.z), f2bf(v3.w)};
        *(ushort4*)&xls[sr][sc]      = u0;
        *(ushort4*)&xls[sr][sc + 4]  = u1;
        *(ushort4*)&xls[sr][sc + 8]  = u2;
        *(ushort4*)&xls[sr][sc + 12] = u3;
    }
    __syncthreads();

    int wave = t >> 6, lane = t & 63, quad = lane >> 4, l15 = lane & 15;
    f32x4 acc[4];
    #pragma unroll
    for (int i = 0; i < 4; i++) acc[i] = (f32x4){0.f, 0.f, 0.f, 0.f};

    #pragma unroll
    for (int ks = 0; ks < 8; ks++) {
        short8 af = *(const short8*)&xls[l15][ks * 32 + quad * 8];
        #pragma unroll
        for (int nt = 0; nt < 4; nt++) {
            short8 bf = *(const short8*)(wswz +
                ((long)((ks * 16 + wave * 4 + nt) * 64 + lane)) * 8);
            acc[nt] = __builtin_amdgcn_mfma_f32_16x16x32_bf16(af, bf, acc[nt], 0, 0, 0);
        }
    }

    // hswz store (B-frag order for k_attn)
    int q0 = (quad & 1) * 4;
    int qd = ((row0 & 31) + quad * 4) >> 3;
    long bj32 = row0 >> 5;
    #pragma unroll
    for (int nt = 0; nt < 4; nt++) {
        int dg = wave * 4 + nt;
        long idx8 = (bj32 * 16 + dg) * 64 + qd * 16 + l15;
        ushort4 o = {f2bf(acc[nt][0]), f2bf(acc[nt][1]),
                     f2bf(acc[nt][2]), f2bf(acc[nt][3])};
        *(ushort4*)&hswz[idx8 * 8 + q0] = o;
    }

    // fused scores, pre-scaled by log2(e)
    float as_[4], ad_[4];
    #pragma unroll
    for (int nt = 0; nt < 4; nt++) {
        int d = nt * 16 + l15;
        as_[nt] = a[d * NH_ + wave];
        ad_[nt] = a[(64 + d) * NH_ + wave];
    }
    #pragma unroll
    for (int r = 0; r < 4; r++) {
        float ps = acc[0][r] * as_[0] + acc[1][r] * as_[1]
                 + acc[2][r] * as_[2] + acc[3][r] * as_[3];
        float pd = acc[0][r] * ad_[0] + acc[1][r] * ad_[1]
                 + acc[2][r] * ad_[2] + acc[3][r] * ad_[3];
        #pragma unroll
        for (int m = 1; m < 16; m <<= 1) {
            ps += __shfl_xor(ps, m);
            pd += __shfl_xor(pd, m);
        }
        if (l15 == 0) {
            int row = n0 + quad * 4 + r;
            ssrc[((long)b * NH_ + wave) * N_ + row] = ps * L2E;
            sdst[((long)b * NH_ + wave) * N_ + row] = pd * L2E;
        }
    }
}

// ---------------------------------------------------------------------------
// Kernel C: fused adj-pack + masked softmax + MFMA aggregate.
// grid = 16 b * 64 itiles(16 rows) = 1024 blocks x 512 thr = 8 waves
// (hh = wave&3, jh = wave>>2). Each wave: one 16-row strip, its j-half.
// Block packs its own adj rows into LDS bitmask words first (1 word/thread).
// Denominator via all-ones-B MFMA. Occupancy cap: 4 blocks/CU, 32 waves/CU.
// ---------------------------------------------------------------------------
__global__ __launch_bounds__(512) void k_attn(
    const int* __restrict__ adj, const unsigned short* __restrict__ hswz,
    const float* __restrict__ ssrc, const float* __restrict__ sdst,
    float* __restrict__ out)
{
    __shared__ unsigned int maskw[16][33];   // [row][word], pad -> conflict-free
    __shared__ float ss_s[4][16];
    __shared__ float accb[4][64][20];        // [hh][lane][16 acc + 4 den]

    int t = threadIdx.x;
    int b  = blockIdx.x >> 6, it = blockIdx.x & 63;
    int i0 = it * 16;
    int wave = t >> 6, lane = t & 63, quad = lane >> 4, l15 = lane & 15;
    int hh = wave & 3, jh = wave >> 2;

    // ---- pack phase: 16 rows x 1024 bits, one word per thread ----
    {
        int row = t >> 5, w = t & 31;
        const int4* ar = (const int4*)(adj + (((long)b * N_ + i0 + row) << 10) + w * 32);
        unsigned int u = 0;
        #pragma unroll
        for (int k = 0; k < 8; k++) {
            int4 av = ar[k];
            u |= ((unsigned)av.x) << (4 * k);
            u |= ((unsigned)av.y) << (4 * k + 1);
            u |= ((unsigned)av.z) << (4 * k + 2);
            u |= ((unsigned)av.w) << (4 * k + 3);
        }
        maskw[row][w] = u;
    }
    if (t < 64) {
        int h = t >> 4, i = t & 15;
        ss_s[h][i] = ssrc[((long)(b * NH_ + h)) * N_ + i0 + i];
    }
    __syncthreads();

    float ssi = ss_s[hh][l15];
    const float* sdp = sdst + ((long)(b * NH_ + hh)) * N_ + jh * 512;

    f32x4 acc[4], dn;
    #pragma unroll
    for (int i = 0; i < 4; i++) acc[i] = (f32x4){0.f, 0.f, 0.f, 0.f};
    dn = (f32x4){0.f, 0.f, 0.f, 0.f};
    short8 ones;
    #pragma unroll
    for (int i = 0; i < 8; i++) ones[i] = (short)0x3F80;   // bf16 1.0

    int shq = quad * 8;

    #pragma unroll 4
    for (int jc = 0; jc < 16; jc++) {
        unsigned int byv = (maskw[l15][jh * 16 + jc] >> shq) & 0xffu;
        const float* sj = sdp + jc * 32 + quad * 8;
        float4 sA = *(const float4*)sj;
        float4 sB = *(const float4*)(sj + 4);
        float sv[8] = {sA.x, sA.y, sA.z, sA.w, sB.x, sB.y, sB.z, sB.w};

        union { unsigned int u[4]; short8 s; } pk;
        #pragma unroll
        for (int qp = 0; qp < 4; qp++) {
            unsigned int wb[2];
            #pragma unroll
            for (int hv = 0; hv < 2; hv++) {
                int q = 2 * qp + hv;
                float e = ssi + sv[q];
                float w = __builtin_exp2f(fmaxf(e, 0.2f * e));
                w = ((byv >> q) & 1u) ? w : 0.f;
                wb[hv] = __float_as_uint(w) + 0x8000u;     // round-half-up
            }
            pk.u[qp] = (wb[1] & 0xffff0000u) | (wb[0] >> 16);
        }

        long s8 = ((long)(b * 32 + jh * 16 + jc)) * 1024;
        #pragma unroll
        for (int idt = 0; idt < 4; idt++) {
            short8 bf = *(const short8*)(hswz + (s8 + (hh * 4 + idt) * 64 + lane) * 8);
            acc[idt] = __builtin_amdgcn_mfma_f32_16x16x32_bf16(pk.s, bf, acc[idt], 0, 0, 0);
        }
        dn = __builtin_amdgcn_mfma_f32_16x16x32_bf16(pk.s, ones, dn, 0, 0, 0);
    }

    if (jh == 1) {
        #pragma unroll
        for (int idt = 0; idt < 4; idt++)
            *(f32x4*)&accb[hh][lane][idt * 4] = acc[idt];
        *(f32x4*)&accb[hh][lane][16] = dn;
    }
    __syncthreads();

    if (jh == 0) {
        f32x4 od = *(const f32x4*)&accb[hh][lane][16];
        float inv[4];
        #pragma unroll
        for (int r = 0; r < 4; r++)
            inv[r] = 1.0f / (dn[r] + od[r]);
        #pragma unroll
        for (int idt = 0; idt < 4; idt++) {
            f32x4 o = *(const f32x4*)&accb[hh][lane][idt * 4];
            int col = hh * 64 + idt * 16 + l15;
            #pragma unroll
            for (int r = 0; r < 4; r++) {
                long row_g = (long)b * N_ + i0 + quad * 4 + r;
                out[row_g * HD_ + col] = (acc[idt][r] + o[r]) * inv[r];
            }
        }
    }
}

extern "C" void kernel_launch(void* const* d_in, const int* in_sizes, int n_in,
                              void* d_out, int out_size, void* d_ws, size_t ws_size,
                              hipStream_t stream) {
    const float* x   = (const float*)d_in[0];
    const int*   adj = (const int*)d_in[1];
    const float* W   = (const float*)d_in[2];
    const float* a   = (const float*)d_in[3];
    float* out = (float*)d_out;

    unsigned short* hswz = (unsigned short*)d_ws;                 // 8 MB
    unsigned short* wswz = hswz + (long)B_ * N_ * HD_;            // 128 KB
    float* ssrc = (float*)(wswz + INF_ * HD_);
    float* sdst = ssrc + (long)B_ * NH_ * N_;

    k_prepw<<<32, 256, 0, stream>>>(W, wswz);
    k_gemm_h<<<1024, 256, 0, stream>>>(x, a, wswz, hswz, ssrc, sdst);
    k_attn<<<1024, 512, 0, stream>>>(adj, hswz, ssrc, sdst, out);
}

// Round 8
// 172.419 us; speedup vs baseline: 1.0069x; 1.0069x over previous
//
#include <hip/hip_runtime.h>
#include <hip/hip_bf16.h>

#define B_   16
#define N_   1024
#define INF_ 256
#define NH_  4
#define HD_  256
#define L2E  1.4426950408889634f

typedef __attribute__((ext_vector_type(8))) short short8;
typedef __attribute__((ext_vector_type(4))) float f32x4;

__device__ __forceinline__ float bf2f(unsigned short u) {
    union { unsigned int i; float f; } v; v.i = ((unsigned int)u) << 16; return v.f;
}
__device__ __forceinline__ unsigned short f2bf(float f) {
    union { float f; unsigned int i; } v; v.f = f;
    unsigned int x = v.i;
    return (unsigned short)((x + 0x7fffu + ((x >> 16) & 1u)) >> 16);
}
// spread 8 bits to every 4th bit position (k -> 4k)
__device__ __forceinline__ unsigned int spread4(unsigned int x) {
    x = (x | (x << 12)) & 0x000F000Fu;
    x = (x | (x << 6))  & 0x03030303u;
    x = (x | (x << 3))  & 0x11111111u;
    return x;
}

// ---------------------------------------------------------------------------
// Kernel PREP (fused, no interdependency):
//  blocks [0,512): adj -> pb row-major bitmask via coalesced int4 + ballot.
//    wave handles 8 rows; per 256-j round: one int4/lane (fully coalesced),
//    4 ballots, lanes 0-7 interleave bytes into words.
//  blocks [512,544): W fp32 -> wswz bf16 in MFMA B-frag order.
// ---------------------------------------------------------------------------
__global__ __launch_bounds__(256) void k_prep(const int* __restrict__ adj,
                                              const float* __restrict__ W,
                                              unsigned int* __restrict__ pb,
                                              unsigned short* __restrict__ wswz)
{
    int bx = blockIdx.x, t = threadIdx.x;
    if (bx < 512) {
        int wave = t >> 6, lane = t & 63;
        int row0 = (bx * 4 + wave) * 8;
        for (int r8 = 0; r8 < 8; r8++) {
            int row = row0 + r8;
            const int4* ar = (const int4*)(adj + ((long)row << 10));
            #pragma unroll
            for (int rd = 0; rd < 4; rd++) {
                int4 av = ar[rd * 64 + lane];
                unsigned long long b0 = __ballot(av.x);
                unsigned long long b1 = __ballot(av.y);
                unsigned long long b2 = __ballot(av.z);
                unsigned long long b3 = __ballot(av.w);
                if (lane < 8) {
                    int sh = lane * 8;
                    unsigned int w =  spread4((unsigned int)(b0 >> sh) & 0xffu)
                                   | (spread4((unsigned int)(b1 >> sh) & 0xffu) << 1)
                                   | (spread4((unsigned int)(b2 >> sh) & 0xffu) << 2)
                                   | (spread4((unsigned int)(b3 >> sh) & 0xffu) << 3);
                    pb[((long)row << 5) + rd * 8 + lane] = w;
                }
            }
        }
    } else {
        int slot = (bx - 512) * 256 + t;
        int kstep = slot >> 10;
        int nt    = (slot >> 6) & 15;
        int lane  = slot & 63;
        int k0 = kstep * 32 + (lane >> 4) * 8;
        int n  = nt * 16 + (lane & 15);
        ushort4 o0, o1;
        o0.x = f2bf(W[(k0 + 0) * HD_ + n]);
        o0.y = f2bf(W[(k0 + 1) * HD_ + n]);
        o0.z = f2bf(W[(k0 + 2) * HD_ + n]);
        o0.w = f2bf(W[(k0 + 3) * HD_ + n]);
        o1.x = f2bf(W[(k0 + 4) * HD_ + n]);
        o1.y = f2bf(W[(k0 + 5) * HD_ + n]);
        o1.z = f2bf(W[(k0 + 6) * HD_ + n]);
        o1.w = f2bf(W[(k0 + 7) * HD_ + n]);
        *(ushort4*)&wswz[(long)slot * 8]     = o0;
        *(ushort4*)&wswz[(long)slot * 8 + 4] = o1;
    }
}

// ---------------------------------------------------------------------------
// Kernel A: h = x @ W via MFMA, W-frags from L2 in-loop (round-6 form).
// Block = 256 thr = 4 waves (one head each), 16 rows. grid = 1024.
// Emits hswz (B-frag order bf16) + scores pre-scaled by log2(e).
// ---------------------------------------------------------------------------
__global__ __launch_bounds__(256) void k_gemm_h(
    const float* __restrict__ x, const float* __restrict__ a,
    const unsigned short* __restrict__ wswz,
    unsigned short* __restrict__ hswz,
    float* __restrict__ ssrc, float* __restrict__ sdst)
{
    __shared__ unsigned short xls[16][264];
    int t = threadIdx.x;
    int blk = blockIdx.x;
    int row0 = blk * 16;
    int b  = blk >> 6;
    int n0 = row0 & 1023;

    {
        int sr = t >> 4, sc = (t & 15) * 16;
        const float* xp = x + (long)(row0 + sr) * INF_ + sc;
        float4 v0 = ((const float4*)xp)[0];
        float4 v1 = ((const float4*)xp)[1];
        float4 v2 = ((const float4*)xp)[2];
        float4 v3 = ((const float4*)xp)[3];
        ushort4 u0 = {f2bf(v0.x), f2bf(v0.y), f2bf(v0.z), f2bf(v0.w)};
        ushort4 u1 = {f2bf(v1.x), f2bf(v1.y), f2bf(v1.z), f2bf(v1.w)};
        ushort4 u2 = {f2bf(v2.x), f2bf(v2.y), f2bf(v2.z), f2bf(v2.w)};
        ushort4 u3 = {f2bf(v3.x), f2bf(v3.y), f2bf(v3.z), f2bf(v3.w)};
        *(ushort4*)&xls[sr][sc]      = u0;
        *(ushort4*)&xls[sr][sc + 4]  = u1;
        *(ushort4*)&xls[sr][sc + 8]  = u2;
        *(ushort4*)&xls[sr][sc + 12] = u3;
    }
    __syncthreads();

    int wave = t >> 6, lane = t & 63, quad = lane >> 4, l15 = lane & 15;
    f32x4 acc[4];
    #pragma unroll
    for (int i = 0; i < 4; i++) acc[i] = (f32x4){0.f, 0.f, 0.f, 0.f};

    #pragma unroll
    for (int ks = 0; ks < 8; ks++) {
        short8 af = *(const short8*)&xls[l15][ks * 32 + quad * 8];
        #pragma unroll
        for (int nt = 0; nt < 4; nt++) {
            short8 bf = *(const short8*)(wswz +
                ((long)((ks * 16 + wave * 4 + nt) * 64 + lane)) * 8);
            acc[nt] = __builtin_amdgcn_mfma_f32_16x16x32_bf16(af, bf, acc[nt], 0, 0, 0);
        }
    }

    // hswz store (B-frag order for k_attn)
    int q0 = (quad & 1) * 4;
    int qd = ((row0 & 31) + quad * 4) >> 3;
    long bj32 = row0 >> 5;
    #pragma unroll
    for (int nt = 0; nt < 4; nt++) {
        int dg = wave * 4 + nt;
        long idx8 = (bj32 * 16 + dg) * 64 + qd * 16 + l15;
        ushort4 o = {f2bf(acc[nt][0]), f2bf(acc[nt][1]),
                     f2bf(acc[nt][2]), f2bf(acc[nt][3])};
        *(ushort4*)&hswz[idx8 * 8 + q0] = o;
    }

    // fused scores, pre-scaled by log2(e)
    float as_[4], ad_[4];
    #pragma unroll
    for (int nt = 0; nt < 4; nt++) {
        int d = nt * 16 + l15;
        as_[nt] = a[d * NH_ + wave];
        ad_[nt] = a[(64 + d) * NH_ + wave];
    }
    #pragma unroll
    for (int r = 0; r < 4; r++) {
        float ps = acc[0][r] * as_[0] + acc[1][r] * as_[1]
                 + acc[2][r] * as_[2] + acc[3][r] * as_[3];
        float pd = acc[0][r] * ad_[0] + acc[1][r] * ad_[1]
                 + acc[2][r] * ad_[2] + acc[3][r] * ad_[3];
        #pragma unroll
        for (int m = 1; m < 16; m <<= 1) {
            ps += __shfl_xor(ps, m);
            pd += __shfl_xor(pd, m);
        }
        if (l15 == 0) {
            int row = n0 + quad * 4 + r;
            ssrc[((long)b * NH_ + wave) * N_ + row] = ps * L2E;
            sdst[((long)b * NH_ + wave) * N_ + row] = pd * L2E;
        }
    }
}

// ---------------------------------------------------------------------------
// Kernel C: masked softmax + MFMA aggregate — zero LDS, zero barriers.
// grid = 16 b * 64 itiles(16 rows) = 1024 blocks x 256 thr = 4 waves
// (wave = head). Each wave: one 16-row strip, FULL j range (32 chunks).
// Mask words from pb (uint4 per 4 chunks); den via all-ones-B MFMA.
// ---------------------------------------------------------------------------
__global__ __launch_bounds__(256) void k_attn(
    const unsigned int* __restrict__ pb, const unsigned short* __restrict__ hswz,
    const float* __restrict__ ssrc, const float* __restrict__ sdst,
    float* __restrict__ out)
{
    int t = threadIdx.x;
    int b  = blockIdx.x >> 6, it = blockIdx.x & 63;
    int i0 = it * 16;
    int hh = t >> 6, lane = t & 63, quad = lane >> 4, l15 = lane & 15;
    int shq = quad * 8;

    float ssi = ssrc[((long)(b * NH_ + hh)) * N_ + i0 + l15];
    const float* sdp = sdst + ((long)(b * NH_ + hh)) * N_;
    const unsigned int* pbrow = pb + (((long)(b * N_ + i0 + l15)) << 5);

    f32x4 acc[4], dn;
    #pragma unroll
    for (int i = 0; i < 4; i++) acc[i] = (f32x4){0.f, 0.f, 0.f, 0.f};
    dn = (f32x4){0.f, 0.f, 0.f, 0.f};
    short8 ones;
    #pragma unroll
    for (int i = 0; i < 8; i++) ones[i] = (short)0x3F80;   // bf16 1.0

    #pragma unroll 4
    for (int jq = 0; jq < 8; jq++) {
        uint4 mq = *(const uint4*)(pbrow + jq * 4);
        #pragma unroll
        for (int js = 0; js < 4; js++) {
            int jc = jq * 4 + js;
            unsigned int mw = (js == 0) ? mq.x : (js == 1) ? mq.y
                             : (js == 2) ? mq.z : mq.w;
            unsigned int byv = (mw >> shq) & 0xffu;

            const float* sj = sdp + jc * 32 + quad * 8;
            float4 sA = *(const float4*)sj;
            float4 sB = *(const float4*)(sj + 4);
            float sv[8] = {sA.x, sA.y, sA.z, sA.w, sB.x, sB.y, sB.z, sB.w};

            union { unsigned int u[4]; short8 s; } pk;
            #pragma unroll
            for (int qp = 0; qp < 4; qp++) {
                unsigned int wb[2];
                #pragma unroll
                for (int hv = 0; hv < 2; hv++) {
                    int q = 2 * qp + hv;
                    float e = ssi + sv[q];
                    float w = __builtin_exp2f(fmaxf(e, 0.2f * e));
                    w = ((byv >> q) & 1u) ? w : 0.f;
                    wb[hv] = __float_as_uint(w) + 0x8000u;   // round-half-up
                }
                pk.u[qp] = (wb[1] & 0xffff0000u) | (wb[0] >> 16);
            }

            long s8 = ((long)(b * 32 + jc)) * 1024;
            #pragma unroll
            for (int idt = 0; idt < 4; idt++) {
                short8 bf = *(const short8*)(hswz + (s8 + (hh * 4 + idt) * 64 + lane) * 8);
                acc[idt] = __builtin_amdgcn_mfma_f32_16x16x32_bf16(pk.s, bf, acc[idt], 0, 0, 0);
            }
            dn = __builtin_amdgcn_mfma_f32_16x16x32_bf16(pk.s, ones, dn, 0, 0, 0);
        }
    }

    // epilogue: C layout col=l15, row=quad*4+r ; dn[r] = den(row) in every col
    float inv[4];
    #pragma unroll
    for (int r = 0; r < 4; r++) inv[r] = 1.0f / dn[r];
    #pragma unroll
    for (int idt = 0; idt < 4; idt++) {
        int col = hh * 64 + idt * 16 + l15;
        #pragma unroll
        for (int r = 0; r < 4; r++) {
            long row_g = (long)b * N_ + i0 + quad * 4 + r;
            out[row_g * HD_ + col] = acc[idt][r] * inv[r];
        }
    }
}

extern "C" void kernel_launch(void* const* d_in, const int* in_sizes, int n_in,
                              void* d_out, int out_size, void* d_ws, size_t ws_size,
                              hipStream_t stream) {
    const float* x   = (const float*)d_in[0];
    const int*   adj = (const int*)d_in[1];
    const float* W   = (const float*)d_in[2];
    const float* a   = (const float*)d_in[3];
    float* out = (float*)d_out;

    unsigned int* pb      = (unsigned int*)d_ws;                       // 2 MB
    unsigned short* hswz  = (unsigned short*)(pb + 524288);            // 8 MB
    unsigned short* wswz  = hswz + (long)B_ * N_ * HD_;                // 128 KB
    float* ssrc = (float*)(wswz + INF_ * HD_);
    float* sdst = ssrc + (long)B_ * NH_ * N_;

    k_prep<<<544, 256, 0, stream>>>(adj, W, pb, wswz);
    k_gemm_h<<<1024, 256, 0, stream>>>(x, a, wswz, hswz, ssrc, sdst);
    k_attn<<<1024, 256, 0, stream>>>(pb, hswz, ssrc, sdst, out);
}

// Round 9
// 158.189 us; speedup vs baseline: 1.0975x; 1.0900x over previous
//
#include <hip/hip_runtime.h>
#include <hip/hip_bf16.h>

#define B_   16
#define N_   1024
#define INF_ 256
#define NH_  4
#define HD_  256
#define L2E  1.4426950408889634f

typedef __attribute__((ext_vector_type(8))) short short8;
typedef __attribute__((ext_vector_type(4))) float f32x4;

__device__ __forceinline__ unsigned short f2bf(float f) {
    union { float f; unsigned int i; } v; v.f = f;
    unsigned int x = v.i;
    return (unsigned short)((x + 0x7fffu + ((x >> 16) & 1u)) >> 16);
}

// ---------------------------------------------------------------------------
// Kernel PREP (fused, independent halves):
//  blocks [0,2048): pack adj -> pb row-major bitmask (bit p of word w =
//    adj[row][w*32+p]); one word/thread, 8 strided int4 loads (max MLP).
//  blocks [2048,2080): W fp32 -> wswz bf16 in MFMA B-frag order.
// ---------------------------------------------------------------------------
__global__ __launch_bounds__(256) void k_prep(const int* __restrict__ adj,
                                              const float* __restrict__ W,
                                              unsigned int* __restrict__ pb,
                                              unsigned short* __restrict__ wswz)
{
    int bx = blockIdx.x, t = threadIdx.x;
    if (bx < 2048) {
        int g = bx * 256 + t;              // word slot [0, 524288)
        int w   = g & 31;
        int row = g >> 5;
        const int* ar = adj + ((long)row << 10) + w * 32;
        unsigned int u = 0;
        #pragma unroll
        for (int k = 0; k < 8; k++) {
            int4 av = *(const int4*)(ar + k * 4);
            u |= ((unsigned)av.x) << (4 * k);
            u |= ((unsigned)av.y) << (4 * k + 1);
            u |= ((unsigned)av.z) << (4 * k + 2);
            u |= ((unsigned)av.w) << (4 * k + 3);
        }
        pb[g] = u;
    } else {
        int slot = (bx - 2048) * 256 + t;
        int kstep = slot >> 10;
        int nt    = (slot >> 6) & 15;
        int lane  = slot & 63;
        int k0 = kstep * 32 + (lane >> 4) * 8;
        int n  = nt * 16 + (lane & 15);
        ushort4 o0, o1;
        o0.x = f2bf(W[(k0 + 0) * HD_ + n]);
        o0.y = f2bf(W[(k0 + 1) * HD_ + n]);
        o0.z = f2bf(W[(k0 + 2) * HD_ + n]);
        o0.w = f2bf(W[(k0 + 3) * HD_ + n]);
        o1.x = f2bf(W[(k0 + 4) * HD_ + n]);
        o1.y = f2bf(W[(k0 + 5) * HD_ + n]);
        o1.z = f2bf(W[(k0 + 6) * HD_ + n]);
        o1.w = f2bf(W[(k0 + 7) * HD_ + n]);
        *(ushort4*)&wswz[(long)slot * 8]     = o0;
        *(ushort4*)&wswz[(long)slot * 8 + 4] = o1;
    }
}

// ---------------------------------------------------------------------------
// Kernel A: h = x @ W via MFMA. W-frags preloaded to registers BEFORE the
// staging barrier (loads overlap staging; MFMA loop = pure LDS+MFMA).
// Block = 256 thr = 4 waves (one head each), 16 rows. grid = 1024.
// Epilogue: hswz (B-frag bf16) + exp2 score factors Ps,Qs,Pd,Qd
// (Pi=2^(L2E*ssrc), Qi=2^(0.2*L2E*ssrc), likewise for sdst).
// ---------------------------------------------------------------------------
__global__ __launch_bounds__(256) void k_gemm_h(
    const float* __restrict__ x, const float* __restrict__ a,
    const unsigned short* __restrict__ wswz,
    unsigned short* __restrict__ hswz,
    float* __restrict__ Ps, float* __restrict__ Qs,
    float* __restrict__ Pd, float* __restrict__ Qd)
{
    __shared__ unsigned short xls[16][264];
    int t = threadIdx.x;
    int blk = blockIdx.x;
    int row0 = blk * 16;
    int b  = blk >> 6;
    int n0 = row0 & 1023;
    int wave = t >> 6, lane = t & 63, quad = lane >> 4, l15 = lane & 15;

    // W-fragment preload (independent of staging -> overlaps it)
    short8 bw[8][4];
    #pragma unroll
    for (int ks = 0; ks < 8; ks++)
        #pragma unroll
        for (int nt = 0; nt < 4; nt++)
            bw[ks][nt] = *(const short8*)(wswz +
                ((long)((ks * 16 + wave * 4 + nt) * 64 + lane)) * 8);

    {
        int sr = t >> 4, sc = (t & 15) * 16;
        const float* xp = x + (long)(row0 + sr) * INF_ + sc;
        float4 v0 = ((const float4*)xp)[0];
        float4 v1 = ((const float4*)xp)[1];
        float4 v2 = ((const float4*)xp)[2];
        float4 v3 = ((const float4*)xp)[3];
        ushort4 u0 = {f2bf(v0.x), f2bf(v0.y), f2bf(v0.z), f2bf(v0.w)};
        ushort4 u1 = {f2bf(v1.x), f2bf(v1.y), f2bf(v1.z), f2bf(v1.w)};
        ushort4 u2 = {f2bf(v2.x), f2bf(v2.y), f2bf(v2.z), f2bf(v2.w)};
        ushort4 u3 = {f2bf(v3.x), f2bf(v3.y), f2bf(v3.z), f2bf(v3.w)};
        *(ushort4*)&xls[sr][sc]      = u0;
        *(ushort4*)&xls[sr][sc + 4]  = u1;
        *(ushort4*)&xls[sr][sc + 8]  = u2;
        *(ushort4*)&xls[sr][sc + 12] = u3;
    }
    __syncthreads();

    f32x4 acc[4];
    #pragma unroll
    for (int i = 0; i < 4; i++) acc[i] = (f32x4){0.f, 0.f, 0.f, 0.f};

    #pragma unroll
    for (int ks = 0; ks < 8; ks++) {
        short8 af = *(const short8*)&xls[l15][ks * 32 + quad * 8];
        #pragma unroll
        for (int nt = 0; nt < 4; nt++)
            acc[nt] = __builtin_amdgcn_mfma_f32_16x16x32_bf16(af, bw[ks][nt], acc[nt], 0, 0, 0);
    }

    // hswz store (B-frag order for k_attn)
    int q0 = (quad & 1) * 4;
    int qd = ((row0 & 31) + quad * 4) >> 3;
    long bj32 = row0 >> 5;
    #pragma unroll
    for (int nt = 0; nt < 4; nt++) {
        int dg = wave * 4 + nt;
        long idx8 = (bj32 * 16 + dg) * 64 + qd * 16 + l15;
        ushort4 o = {f2bf(acc[nt][0]), f2bf(acc[nt][1]),
                     f2bf(acc[nt][2]), f2bf(acc[nt][3])};
        *(ushort4*)&hswz[idx8 * 8 + q0] = o;
    }

    // fused scores -> exp2 factor arrays
    float as_[4], ad_[4];
    #pragma unroll
    for (int nt = 0; nt < 4; nt++) {
        int d = nt * 16 + l15;
        as_[nt] = a[d * NH_ + wave];
        ad_[nt] = a[(64 + d) * NH_ + wave];
    }
    #pragma unroll
    for (int r = 0; r < 4; r++) {
        float ps = acc[0][r] * as_[0] + acc[1][r] * as_[1]
                 + acc[2][r] * as_[2] + acc[3][r] * as_[3];
        float pd = acc[0][r] * ad_[0] + acc[1][r] * ad_[1]
                 + acc[2][r] * ad_[2] + acc[3][r] * ad_[3];
        #pragma unroll
        for (int m = 1; m < 16; m <<= 1) {
            ps += __shfl_xor(ps, m);
            pd += __shfl_xor(pd, m);
        }
        if (l15 == 0) {
            int row = n0 + quad * 4 + r;
            long o = ((long)b * NH_ + wave) * N_ + row;
            float ss = ps * L2E, sd = pd * L2E;
            Ps[o] = __builtin_exp2f(ss);
            Qs[o] = __builtin_exp2f(0.2f * ss);
            Pd[o] = __builtin_exp2f(sd);
            Qd[o] = __builtin_exp2f(0.2f * sd);
        }
    }
}

// ---------------------------------------------------------------------------
// Kernel C: masked softmax + MFMA aggregate (round-6 structure, product
// w-phase). grid = 16 b * 32 rowgroups(32 rows) = 512 blocks x 512 thr =
// 8 waves (hh = wave&3, jh = wave>>2); each wave 2 i-strips (B-frag reuse).
// w = max(Pi*Pj, Qi*Qj) [== exp2(lrelu(si+sj))], masked by pb bit.
// Denominator via all-ones-B MFMA.
// ---------------------------------------------------------------------------
__global__ __launch_bounds__(512, 4) void k_attn(
    const unsigned int* __restrict__ pb, const unsigned short* __restrict__ hswz,
    const float* __restrict__ Ps, const float* __restrict__ Qs,
    const float* __restrict__ Pd, const float* __restrict__ Qd,
    float* __restrict__ out)
{
    __shared__ float ps_s[4][32], qs_s[4][32];
    __shared__ float accb[4][2][64][20];   // [hh][strip][lane][16 acc + 4 den]

    int t = threadIdx.x;
    int b  = blockIdx.x >> 5, ig = blockIdx.x & 31;
    int i0 = ig * 32;
    int wave = t >> 6, lane = t & 63, quad = lane >> 4, l15 = lane & 15;
    int hh = wave & 3, jh = wave >> 2;

    if (t < 128) {
        int h = t >> 5, i = t & 31;
        long o = ((long)(b * NH_ + h)) * N_ + i0 + i;
        ps_s[h][i] = Ps[o];
        qs_s[h][i] = Qs[o];
    }
    __syncthreads();

    float Pi0 = ps_s[hh][l15],      Qi0 = qs_s[hh][l15];
    float Pi1 = ps_s[hh][16 + l15], Qi1 = qs_s[hh][16 + l15];
    const float* Pdp = Pd + ((long)(b * NH_ + hh)) * N_ + jh * 512;
    const float* Qdp = Qd + ((long)(b * NH_ + hh)) * N_ + jh * 512;
    long grow0 = ((long)b << 10) + i0 + l15;
    const unsigned int* pb0 = pb + (grow0 << 5) + jh * 16;
    const unsigned int* pb1 = pb0 + (16 << 5);

    f32x4 acc0[4], acc1[4], dn0, dn1;
    #pragma unroll
    for (int i = 0; i < 4; i++) {
        acc0[i] = (f32x4){0.f, 0.f, 0.f, 0.f};
        acc1[i] = (f32x4){0.f, 0.f, 0.f, 0.f};
    }
    dn0 = (f32x4){0.f, 0.f, 0.f, 0.f};
    dn1 = (f32x4){0.f, 0.f, 0.f, 0.f};
    short8 ones;
    #pragma unroll
    for (int i = 0; i < 8; i++) ones[i] = (short)0x3F80;   // bf16 1.0

    int shq = quad * 8;

    #pragma unroll 4
    for (int jc = 0; jc < 16; jc++) {
        unsigned int m0 = (pb0[jc] >> shq) & 0xffu;
        unsigned int m1 = (pb1[jc] >> shq) & 0xffu;
        const float* pj = Pdp + jc * 32 + quad * 8;
        const float* qj = Qdp + jc * 32 + quad * 8;
        float4 pA = *(const float4*)pj;
        float4 pB = *(const float4*)(pj + 4);
        float4 qA = *(const float4*)qj;
        float4 qB = *(const float4*)(qj + 4);
        float pv[8] = {pA.x, pA.y, pA.z, pA.w, pB.x, pB.y, pB.z, pB.w};
        float qv[8] = {qA.x, qA.y, qA.z, qA.w, qB.x, qB.y, qB.z, qB.w};

        union { unsigned int u[4]; short8 s; } pk0, pk1;
        #pragma unroll
        for (int qp = 0; qp < 4; qp++) {
            unsigned int wb0[2], wb1[2];
            #pragma unroll
            for (int hv = 0; hv < 2; hv++) {
                int q = 2 * qp + hv;
                float w0 = fmaxf(Pi0 * pv[q], Qi0 * qv[q]);
                w0 = ((m0 >> q) & 1u) ? w0 : 0.f;
                wb0[hv] = __float_as_uint(w0) + 0x8000u;   // round-half-up
                float w1 = fmaxf(Pi1 * pv[q], Qi1 * qv[q]);
                w1 = ((m1 >> q) & 1u) ? w1 : 0.f;
                wb1[hv] = __float_as_uint(w1) + 0x8000u;
            }
            pk0.u[qp] = (wb0[1] & 0xffff0000u) | (wb0[0] >> 16);
            pk1.u[qp] = (wb1[1] & 0xffff0000u) | (wb1[0] >> 16);
        }

        long s8 = ((long)(b * 32 + jh * 16 + jc)) * 1024;
        #pragma unroll
        for (int idt = 0; idt < 4; idt++) {
            short8 bf = *(const short8*)(hswz + (s8 + (hh * 4 + idt) * 64 + lane) * 8);
            acc0[idt] = __builtin_amdgcn_mfma_f32_16x16x32_bf16(pk0.s, bf, acc0[idt], 0, 0, 0);
            acc1[idt] = __builtin_amdgcn_mfma_f32_16x16x32_bf16(pk1.s, bf, acc1[idt], 0, 0, 0);
        }
        dn0 = __builtin_amdgcn_mfma_f32_16x16x32_bf16(pk0.s, ones, dn0, 0, 0, 0);
        dn1 = __builtin_amdgcn_mfma_f32_16x16x32_bf16(pk1.s, ones, dn1, 0, 0, 0);
    }

    if (jh == 1) {
        #pragma unroll
        for (int idt = 0; idt < 4; idt++) {
            *(f32x4*)&accb[hh][0][lane][idt * 4] = acc0[idt];
            *(f32x4*)&accb[hh][1][lane][idt * 4] = acc1[idt];
        }
        *(f32x4*)&accb[hh][0][lane][16] = dn0;
        *(f32x4*)&accb[hh][1][lane][16] = dn1;
    }
    __syncthreads();

    if (jh == 0) {
        f32x4 od0 = *(const f32x4*)&accb[hh][0][lane][16];
        f32x4 od1 = *(const f32x4*)&accb[hh][1][lane][16];
        float inv0[4], inv1[4];
        #pragma unroll
        for (int r = 0; r < 4; r++) {
            inv0[r] = 1.0f / (dn0[r] + od0[r]);
            inv1[r] = 1.0f / (dn1[r] + od1[r]);
        }
        #pragma unroll
        for (int idt = 0; idt < 4; idt++) {
            f32x4 o0 = *(const f32x4*)&accb[hh][0][lane][idt * 4];
            f32x4 o1 = *(const f32x4*)&accb[hh][1][lane][idt * 4];
            int col = hh * 64 + idt * 16 + l15;
            #pragma unroll
            for (int r = 0; r < 4; r++) {
                long row_g = (long)b * N_ + i0 + quad * 4 + r;
                out[row_g * HD_ + col] = (acc0[idt][r] + o0[r]) * inv0[r];
                out[(row_g + 16) * HD_ + col] = (acc1[idt][r] + o1[r]) * inv1[r];
            }
        }
    }
}

extern "C" void kernel_launch(void* const* d_in, const int* in_sizes, int n_in,
                              void* d_out, int out_size, void* d_ws, size_t ws_size,
                              hipStream_t stream) {
    const float* x   = (const float*)d_in[0];
    const int*   adj = (const int*)d_in[1];
    const float* W   = (const float*)d_in[2];
    const float* a   = (const float*)d_in[3];
    float* out = (float*)d_out;

    unsigned int* pb      = (unsigned int*)d_ws;                       // 2 MB
    unsigned short* hswz  = (unsigned short*)(pb + 524288);            // 8 MB
    unsigned short* wswz  = hswz + (long)B_ * N_ * HD_;                // 128 KB
    float* Ps = (float*)(wswz + INF_ * HD_);                           // 256 KB each
    float* Qs = Ps + (long)B_ * NH_ * N_;
    float* Pd = Qs + (long)B_ * NH_ * N_;
    float* Qd = Pd + (long)B_ * NH_ * N_;

    k_prep<<<2080, 256, 0, stream>>>(adj, W, pb, wswz);
    k_gemm_h<<<1024, 256, 0, stream>>>(x, a, wswz, hswz, Ps, Qs, Pd, Qd);
    k_attn<<<512, 512, 0, stream>>>(pb, hswz, Ps, Qs, Pd, Qd, out);
}